// Round 1
// baseline (1447.911 us; speedup 1.0000x reference)
//
#include <hip/hip_runtime.h>

// Problem constants (match reference setup_inputs)
#define N_NODES 50000
#define N_EDGES 800000
#define F_INF   64
#define C_CH    100
#define T_OUT   8

__device__ __forceinline__ float sigmoidf_(float x) {
    return 1.0f / (1.0f + __expf(-x));
}
__device__ __forceinline__ float tanhf_(float x) {
    // tanh(x) = 1 - 2/(exp(2x)+1); exact limits at +-inf
    return 1.0f - 2.0f / (__expf(2.0f * x) + 1.0f);
}

// ---------------------------------------------------------------------------
// K1: m[n,j] = sum_{k<64} x[n,k] * Wg[k*100+j]   (xp padded to 100, so only
// first 64 rows of ggc_w[0] contribute).  One thread per (n,j) element.
// ---------------------------------------------------------------------------
__global__ void k_m(const float* __restrict__ x, const float* __restrict__ Wg,
                    float* __restrict__ m) {
    __shared__ float Ws[F_INF * C_CH];  // 25.6 KB
    for (int i = threadIdx.x; i < F_INF * C_CH; i += blockDim.x) Ws[i] = Wg[i];
    __syncthreads();
    int i = blockIdx.x * blockDim.x + threadIdx.x;
    if (i >= N_NODES * C_CH) return;
    int n = i / C_CH;
    int j = i - n * C_CH;
    const float* xr = x + n * F_INF;
    float acc = 0.0f;
#pragma unroll 8
    for (int k = 0; k < F_INF; ++k) acc += xr[k] * Ws[k * C_CH + j];
    m[i] = acc;
}

// ---------------------------------------------------------------------------
// K2a: in-degree count
// ---------------------------------------------------------------------------
__global__ void k_cnt(const int* __restrict__ ei, float* __restrict__ cnt) {
    int e = blockIdx.x * blockDim.x + threadIdx.x;
    if (e >= N_EDGES) return;
    int d = ei[N_EDGES + e];
    atomicAdd(&cnt[d], 1.0f);
}

// ---------------------------------------------------------------------------
// K2b: scatter-add  summ[dst, j] += m[src, j] * w[e]
// one thread per (edge, channel)
// ---------------------------------------------------------------------------
__global__ void k_scatter(const int* __restrict__ ei, const float* __restrict__ ew,
                          const float* __restrict__ m, float* __restrict__ summ) {
    int i = blockIdx.x * blockDim.x + threadIdx.x;
    if (i >= N_EDGES * C_CH) return;
    int e = i / C_CH;
    int j = i - e * C_CH;
    int s = ei[e];
    int d = ei[N_EDGES + e];
    float v = m[s * C_CH + j] * ew[e];
    atomicAdd(&summ[d * C_CH + j], v);
}

// ---------------------------------------------------------------------------
// K3: GRUCell -> conv_h.  Block = 256 threads = 64 nodes x 4 channel-groups.
// agg and x tiles staged in LDS (conflict-free strides); weights are
// wave-uniform broadcast loads from global (L2 resident).
// ---------------------------------------------------------------------------
__global__ void k_gru(const float* __restrict__ x, const float* __restrict__ summ,
                      const float* __restrict__ cnt,
                      const float* __restrict__ Wih, const float* __restrict__ Whh,
                      const float* __restrict__ bih, const float* __restrict__ bhh,
                      float* __restrict__ convh) {
    __shared__ float ags[64 * 101];  // stride 101 -> banks (5*nl+k)%32, conflict-free
    __shared__ float xs[64 * 65];    // stride 65  -> banks (nl+k)%32, conflict-free
    int n0 = blockIdx.x * 64;

    for (int idx = threadIdx.x; idx < 64 * C_CH; idx += 256) {
        int nl = idx / C_CH;
        int k  = idx - nl * C_CH;
        int n  = n0 + nl;
        float v = 0.0f;
        if (n < N_NODES) {
            float ct = fmaxf(cnt[n], 1.0f);
            v = summ[n * C_CH + k] / ct;
        }
        ags[nl * 101 + k] = v;
    }
    for (int idx = threadIdx.x; idx < 64 * F_INF; idx += 256) {
        int nl = idx >> 6;
        int k  = idx & 63;
        int n  = n0 + nl;
        xs[nl * 65 + k] = (n < N_NODES) ? x[n * F_INF + k] : 0.0f;
    }
    __syncthreads();

    int nl = threadIdx.x & 63;
    int jt = threadIdx.x >> 6;
    int n  = n0 + nl;
    if (n >= N_NODES) return;
    const float* ag = &ags[nl * 101];
    const float* xr = &xs[nl * 65];

    for (int c = jt; c < C_CH; c += 4) {
        float ir = bih[c], iz = bih[C_CH + c], inn = bih[2 * C_CH + c];
        const float* wr = Wih + (size_t)c * C_CH;
        const float* wz = Wih + (size_t)(C_CH + c) * C_CH;
        const float* wn = Wih + (size_t)(2 * C_CH + c) * C_CH;
#pragma unroll 4
        for (int k = 0; k < C_CH; ++k) {
            float a = ag[k];
            ir  += a * wr[k];
            iz  += a * wz[k];
            inn += a * wn[k];
        }
        float hr = bhh[c], hz = bhh[C_CH + c], hn = bhh[2 * C_CH + c];
        const float* vr = Whh + (size_t)c * C_CH;
        const float* vz = Whh + (size_t)(C_CH + c) * C_CH;
        const float* vn = Whh + (size_t)(2 * C_CH + c) * C_CH;
#pragma unroll 4
        for (int k = 0; k < F_INF; ++k) {
            float xv = xr[k];
            hr += xv * vr[k];
            hz += xv * vz[k];
            hn += xv * vn[k];
        }
        float r  = sigmoidf_(ir + hr);
        float z  = sigmoidf_(iz + hz);
        float ng = tanhf_(inn + r * hn);
        float xpc = (c < F_INF) ? xr[c] : 0.0f;
        convh[(size_t)n * C_CH + c] = (1.0f - z) * ng + z * xpc;
    }
}

// ---------------------------------------------------------------------------
// K4: LSTM single step -> h1, c1 (written straight into d_out).
// Block = 256 threads = 64 nodes x 4 channel-groups.
// ---------------------------------------------------------------------------
__global__ void k_lstm(const float* __restrict__ convh, const float* __restrict__ h0,
                       const float* __restrict__ c0,
                       const float* __restrict__ Wih, const float* __restrict__ Whh,
                       const float* __restrict__ bih, const float* __restrict__ bhh,
                       float* __restrict__ h1, float* __restrict__ c1) {
    __shared__ float cs[64 * 101];
    __shared__ float hs[64 * 65];
    int n0 = blockIdx.x * 64;

    for (int idx = threadIdx.x; idx < 64 * C_CH; idx += 256) {
        int nl = idx / C_CH;
        int k  = idx - nl * C_CH;
        int n  = n0 + nl;
        cs[nl * 101 + k] = (n < N_NODES) ? convh[(size_t)n * C_CH + k] : 0.0f;
    }
    for (int idx = threadIdx.x; idx < 64 * F_INF; idx += 256) {
        int nl = idx >> 6;
        int k  = idx & 63;
        int n  = n0 + nl;
        hs[nl * 65 + k] = (n < N_NODES) ? h0[(size_t)n * F_INF + k] : 0.0f;
    }
    __syncthreads();

    int nl = threadIdx.x & 63;
    int jt = threadIdx.x >> 6;
    int n  = n0 + nl;
    if (n >= N_NODES) return;
    const float* cr = &cs[nl * 101];
    const float* hr = &hs[nl * 65];

    for (int ch = jt; ch < F_INF; ch += 4) {
        float gi = bih[ch]           + bhh[ch];
        float gf = bih[F_INF + ch]   + bhh[F_INF + ch];
        float gg = bih[2*F_INF + ch] + bhh[2*F_INF + ch];
        float go = bih[3*F_INF + ch] + bhh[3*F_INF + ch];
        const float* wi = Wih + (size_t)ch * C_CH;
        const float* wf = Wih + (size_t)(F_INF + ch) * C_CH;
        const float* wg = Wih + (size_t)(2*F_INF + ch) * C_CH;
        const float* wo = Wih + (size_t)(3*F_INF + ch) * C_CH;
#pragma unroll 4
        for (int k = 0; k < C_CH; ++k) {
            float cv = cr[k];
            gi += cv * wi[k];
            gf += cv * wf[k];
            gg += cv * wg[k];
            go += cv * wo[k];
        }
        const float* ui = Whh + (size_t)ch * F_INF;
        const float* uf = Whh + (size_t)(F_INF + ch) * F_INF;
        const float* ug = Whh + (size_t)(2*F_INF + ch) * F_INF;
        const float* uo = Whh + (size_t)(3*F_INF + ch) * F_INF;
#pragma unroll 4
        for (int k = 0; k < F_INF; ++k) {
            float hv = hr[k];
            gi += hv * ui[k];
            gf += hv * uf[k];
            gg += hv * ug[k];
            go += hv * uo[k];
        }
        float ig = sigmoidf_(gi);
        float fg = sigmoidf_(gf);
        float g  = tanhf_(gg);
        float og = sigmoidf_(go);
        float cc = fg * c0[(size_t)n * F_INF + ch] + ig * g;
        float hh = og * tanhf_(cc);
        c1[(size_t)n * F_INF + ch] = cc;
        h1[(size_t)n * F_INF + ch] = hh;
    }
}

// ---------------------------------------------------------------------------
// K5: out[n,t] = relu(h1[n,:]) @ lin_w[t,:] + lin_b[t]
// ---------------------------------------------------------------------------
__global__ void k_head(const float* __restrict__ h1, const float* __restrict__ lw,
                       const float* __restrict__ lb, float* __restrict__ out) {
    int i = blockIdx.x * blockDim.x + threadIdx.x;
    if (i >= N_NODES * T_OUT) return;
    int n = i >> 3;
    int t = i & 7;
    const float* hr = h1 + (size_t)n * F_INF;
    const float* wr = lw + (size_t)t * F_INF;
    float acc = lb[t];
#pragma unroll 8
    for (int k = 0; k < F_INF; ++k) acc += fmaxf(hr[k], 0.0f) * wr[k];
    out[i] = acc;
}

extern "C" void kernel_launch(void* const* d_in, const int* in_sizes, int n_in,
                              void* d_out, int out_size, void* d_ws, size_t ws_size,
                              hipStream_t stream) {
    const float* x     = (const float*)d_in[0];
    const int*   ei    = (const int*)d_in[1];
    const float* ew    = (const float*)d_in[2];
    const float* h0    = (const float*)d_in[3];
    const float* c0    = (const float*)d_in[4];
    const float* ggc   = (const float*)d_in[5];
    const float* gwih  = (const float*)d_in[6];
    const float* gwhh  = (const float*)d_in[7];
    const float* gbih  = (const float*)d_in[8];
    const float* gbhh  = (const float*)d_in[9];
    const float* lwih  = (const float*)d_in[10];
    const float* lwhh  = (const float*)d_in[11];
    const float* lbih  = (const float*)d_in[12];
    const float* lbhh  = (const float*)d_in[13];
    const float* lw    = (const float*)d_in[14];
    const float* lb    = (const float*)d_in[15];

    float* out = (float*)d_out;                  // [N, 8]
    float* h1  = out + (size_t)N_NODES * T_OUT;  // [N, 64]
    float* c1  = h1 + (size_t)N_NODES * F_INF;   // [N, 64]

    float* ws    = (float*)d_ws;
    float* m     = ws;                           // N*C
    float* summ  = m + (size_t)N_NODES * C_CH;   // N*C
    float* cnt   = summ + (size_t)N_NODES * C_CH;// N
    float* convh = cnt + N_NODES;                // N*C

    // zero summ + cnt (contiguous)
    hipMemsetAsync(summ, 0, ((size_t)N_NODES * C_CH + N_NODES) * sizeof(float), stream);

    {
        int total = N_NODES * C_CH;
        int blocks = (total + 255) / 256;
        k_m<<<blocks, 256, 0, stream>>>(x, ggc, m);
    }
    {
        int blocks = (N_EDGES + 255) / 256;
        k_cnt<<<blocks, 256, 0, stream>>>(ei, cnt);
    }
    {
        long long total = (long long)N_EDGES * C_CH;  // 80M
        int blocks = (int)((total + 255) / 256);
        k_scatter<<<blocks, 256, 0, stream>>>(ei, ew, m, summ);
    }
    {
        int blocks = (N_NODES + 63) / 64;
        k_gru<<<blocks, 256, 0, stream>>>(x, summ, cnt, gwih, gwhh, gbih, gbhh, convh);
    }
    {
        int blocks = (N_NODES + 63) / 64;
        k_lstm<<<blocks, 256, 0, stream>>>(convh, h0, c0, lwih, lwhh, lbih, lbhh, h1, c1);
    }
    {
        int total = N_NODES * T_OUT;
        int blocks = (total + 255) / 256;
        k_head<<<blocks, 256, 0, stream>>>(h1, lw, lb, out);
    }
}

// Round 2
// 926.707 us; speedup vs baseline: 1.5624x; 1.5624x over previous
//
#include <hip/hip_runtime.h>

// Problem constants (match reference setup_inputs)
#define N_NODES 50000
#define N_EDGES 800000
#define F_INF   64
#define C_CH    100
#define T_OUT   8

__device__ __forceinline__ float sigmoidf_(float x) {
    return 1.0f / (1.0f + __expf(-x));
}
__device__ __forceinline__ float tanhf_(float x) {
    return 1.0f - 2.0f / (__expf(2.0f * x) + 1.0f);
}
__device__ __forceinline__ float dot4_(float4 a, float4 b, float acc) {
    acc += a.x * b.x; acc += a.y * b.y; acc += a.z * b.z; acc += a.w * b.w;
    return acc;
}

// ---------------------------------------------------------------------------
// K1: m[n,j] = sum_{k<64} x[n,k] * Wg[k*100+j]
// ---------------------------------------------------------------------------
__global__ void k_m(const float* __restrict__ x, const float* __restrict__ Wg,
                    float* __restrict__ m) {
    __shared__ float Ws[F_INF * C_CH];  // 25.6 KB
    for (int i = threadIdx.x; i < F_INF * C_CH; i += blockDim.x) Ws[i] = Wg[i];
    __syncthreads();
    int i = blockIdx.x * blockDim.x + threadIdx.x;
    if (i >= N_NODES * C_CH) return;
    int n = i / C_CH;
    int j = i - n * C_CH;
    const float* xr = x + n * F_INF;
    float acc = 0.0f;
#pragma unroll 8
    for (int k = 0; k < F_INF; ++k) acc += xr[k] * Ws[k * C_CH + j];
    m[i] = acc;
}

// ---------------------------------------------------------------------------
// K2a: in-degree count
// ---------------------------------------------------------------------------
__global__ void k_cnt(const int* __restrict__ ei, float* __restrict__ cnt) {
    int e = blockIdx.x * blockDim.x + threadIdx.x;
    if (e >= N_EDGES) return;
    int d = ei[N_EDGES + e];
    atomicAdd(&cnt[d], 1.0f);
}

// ---------------------------------------------------------------------------
// K2b: scatter-add  summ[dst, j] += m[src, j] * w[e]
// ---------------------------------------------------------------------------
__global__ void k_scatter(const int* __restrict__ ei, const float* __restrict__ ew,
                          const float* __restrict__ m, float* __restrict__ summ) {
    int i = blockIdx.x * blockDim.x + threadIdx.x;
    if (i >= N_EDGES * C_CH) return;
    int e = i / C_CH;
    int j = i - e * C_CH;
    int s = ei[e];
    int d = ei[N_EDGES + e];
    float v = m[s * C_CH + j] * ew[e];
    atomicAdd(&summ[d * C_CH + j], v);
}

// ---------------------------------------------------------------------------
// K3: GRUCell -> conv_h.  Block = 512 threads, 128 nodes.
// act row = [agg(100) | x(64)] in LDS, stride 164 floats (41 float4 -> odd
// quad stride, conflict-free b128).  Weights LDS-tiled 32 channels at a time.
// Thread = 4 nodes (nl4, +32, +64, +96... nl4+32r) x 2 channels.
// LDS: 84 + 38.4 + 24.6 = 147 KB -> 1 block/CU, 8 waves.
// ---------------------------------------------------------------------------
__global__ __launch_bounds__(512) void k_gru(
    const float* __restrict__ x, const float* __restrict__ summ,
    const float* __restrict__ cnt,
    const float* __restrict__ Wih, const float* __restrict__ Whh,
    const float* __restrict__ bih, const float* __restrict__ bhh,
    float* __restrict__ convh) {
    __shared__ float4 acts4[128 * 41];     // 84 KB
    __shared__ float4 wih4[3 * 32 * 25];   // 38.4 KB
    __shared__ float4 whh4[3 * 32 * 16];   // 24.6 KB
    const float* acts = (const float*)acts4;
    int tid = threadIdx.x;
    int n0 = blockIdx.x * 128;

    // stage activations: agg = summ / max(cnt,1)
    for (int idx = tid; idx < 128 * 25; idx += 512) {
        int nl = idx / 25, k4 = idx - nl * 25;
        int n = n0 + nl;
        float4 v = make_float4(0.f, 0.f, 0.f, 0.f);
        if (n < N_NODES) {
            float rc = 1.0f / fmaxf(cnt[n], 1.0f);
            float4 s = ((const float4*)summ)[n * 25 + k4];
            v = make_float4(s.x * rc, s.y * rc, s.z * rc, s.w * rc);
        }
        acts4[nl * 41 + k4] = v;
    }
    for (int idx = tid; idx < 128 * 16; idx += 512) {
        int nl = idx >> 4, k4 = idx & 15;
        int n = n0 + nl;
        float4 v = make_float4(0.f, 0.f, 0.f, 0.f);
        if (n < N_NODES) v = ((const float4*)x)[n * 16 + k4];
        acts4[nl * 41 + 25 + k4] = v;
    }

    int nl4 = tid & 31;
    int jt  = tid >> 5;  // 0..15

    for (int c0 = 0; c0 < C_CH; c0 += 32) {
        int tc = min(32, C_CH - c0);
        __syncthreads();
        // stage weight tile
        for (int idx = tid; idx < 3 * tc * 25; idx += 512) {
            int g = idx / (tc * 25); int r2 = idx - g * tc * 25;
            int cl = r2 / 25; int k4 = r2 - cl * 25;
            wih4[(g * 32 + cl) * 25 + k4] =
                ((const float4*)Wih)[(g * C_CH + c0 + cl) * 25 + k4];
        }
        for (int idx = tid; idx < 3 * tc * 16; idx += 512) {
            int g = idx / (tc * 16); int r2 = idx - g * tc * 16;
            int cl = r2 >> 4; int k4 = r2 & 15;
            whh4[(g * 32 + cl) * 16 + k4] =
                ((const float4*)Whh)[(g * C_CH + c0 + cl) * 25 + k4];
        }
        __syncthreads();

        int cl0 = 2 * jt;
        if (cl0 >= tc) continue;
        int c = c0 + cl0;

        float ar0[4], az0[4], an0[4], hn0[4];
        float ar1[4], az1[4], an1[4], hn1[4];
        {
            float br0 = bih[c] + bhh[c];
            float bz0 = bih[C_CH + c] + bhh[C_CH + c];
            float bn0 = bih[2 * C_CH + c];
            float bhn0 = bhh[2 * C_CH + c];
            float br1 = bih[c + 1] + bhh[c + 1];
            float bz1 = bih[C_CH + c + 1] + bhh[C_CH + c + 1];
            float bn1 = bih[2 * C_CH + c + 1];
            float bhn1 = bhh[2 * C_CH + c + 1];
#pragma unroll
            for (int r = 0; r < 4; ++r) {
                ar0[r] = br0; az0[r] = bz0; an0[r] = bn0; hn0[r] = bhn0;
                ar1[r] = br1; az1[r] = bz1; an1[r] = bn1; hn1[r] = bhn1;
            }
        }
        const float4* wr0 = wih4 + (0 * 32 + cl0) * 25;
        const float4* wz0 = wih4 + (1 * 32 + cl0) * 25;
        const float4* wn0 = wih4 + (2 * 32 + cl0) * 25;
        // ih part: k = 0..99 (agg)
        for (int k4 = 0; k4 < 25; ++k4) {
            float4 wra = wr0[k4], wrb = wr0[25 + k4];
            float4 wza = wz0[k4], wzb = wz0[25 + k4];
            float4 wna = wn0[k4], wnb = wn0[25 + k4];
#pragma unroll
            for (int r = 0; r < 4; ++r) {
                float4 a = acts4[(nl4 + 32 * r) * 41 + k4];
                ar0[r] = dot4_(a, wra, ar0[r]);
                ar1[r] = dot4_(a, wrb, ar1[r]);
                az0[r] = dot4_(a, wza, az0[r]);
                az1[r] = dot4_(a, wzb, az1[r]);
                an0[r] = dot4_(a, wna, an0[r]);
                an1[r] = dot4_(a, wnb, an1[r]);
            }
        }
        const float4* ur0 = whh4 + (0 * 32 + cl0) * 16;
        const float4* uz0 = whh4 + (1 * 32 + cl0) * 16;
        const float4* un0 = whh4 + (2 * 32 + cl0) * 16;
        // hh part: k = 0..63 (x)
        for (int k4 = 0; k4 < 16; ++k4) {
            float4 wra = ur0[k4], wrb = ur0[16 + k4];
            float4 wza = uz0[k4], wzb = uz0[16 + k4];
            float4 wna = un0[k4], wnb = un0[16 + k4];
#pragma unroll
            for (int r = 0; r < 4; ++r) {
                float4 a = acts4[(nl4 + 32 * r) * 41 + 25 + k4];
                ar0[r] = dot4_(a, wra, ar0[r]);
                ar1[r] = dot4_(a, wrb, ar1[r]);
                az0[r] = dot4_(a, wza, az0[r]);
                az1[r] = dot4_(a, wzb, az1[r]);
                hn0[r] = dot4_(a, wna, hn0[r]);
                hn1[r] = dot4_(a, wnb, hn1[r]);
            }
        }
#pragma unroll
        for (int r = 0; r < 4; ++r) {
            int n = n0 + nl4 + 32 * r;
            if (n >= N_NODES) continue;
            float rr = sigmoidf_(ar0[r]);
            float zz = sigmoidf_(az0[r]);
            float nn = tanhf_(an0[r] + rr * hn0[r]);
            float xpc = (c < F_INF) ? acts[(nl4 + 32 * r) * 164 + 100 + c] : 0.0f;
            convh[(size_t)n * C_CH + c] = (1.0f - zz) * nn + zz * xpc;
            rr = sigmoidf_(ar1[r]);
            zz = sigmoidf_(az1[r]);
            nn = tanhf_(an1[r] + rr * hn1[r]);
            xpc = (c + 1 < F_INF) ? acts[(nl4 + 32 * r) * 164 + 100 + c + 1] : 0.0f;
            convh[(size_t)n * C_CH + c + 1] = (1.0f - zz) * nn + zz * xpc;
        }
    }
}

// ---------------------------------------------------------------------------
// K4: LSTM single step -> h1, c1.  Block = 512 threads, 128 nodes.
// act row = [convh(100) | h0(64)], stride 41 float4.  Weights LDS-tiled 16
// output channels at a time (4 tiles).  Thread = 4 nodes x 1 channel x 4 gates.
// LDS: 84 + 25.6 + 16.4 = 126 KB -> 1 block/CU.
// ---------------------------------------------------------------------------
__global__ __launch_bounds__(512) void k_lstm(
    const float* __restrict__ convh, const float* __restrict__ h0,
    const float* __restrict__ c0in,
    const float* __restrict__ Wih, const float* __restrict__ Whh,
    const float* __restrict__ bih, const float* __restrict__ bhh,
    float* __restrict__ h1, float* __restrict__ c1) {
    __shared__ float4 acts4[128 * 41];     // 84 KB
    __shared__ float4 wih4[4 * 16 * 25];   // 25.6 KB
    __shared__ float4 whh4[4 * 16 * 16];   // 16.4 KB
    int tid = threadIdx.x;
    int n0 = blockIdx.x * 128;

    for (int idx = tid; idx < 128 * 25; idx += 512) {
        int nl = idx / 25, k4 = idx - nl * 25;
        int n = n0 + nl;
        float4 v = make_float4(0.f, 0.f, 0.f, 0.f);
        if (n < N_NODES) v = ((const float4*)convh)[n * 25 + k4];
        acts4[nl * 41 + k4] = v;
    }
    for (int idx = tid; idx < 128 * 16; idx += 512) {
        int nl = idx >> 4, k4 = idx & 15;
        int n = n0 + nl;
        float4 v = make_float4(0.f, 0.f, 0.f, 0.f);
        if (n < N_NODES) v = ((const float4*)h0)[n * 16 + k4];
        acts4[nl * 41 + 25 + k4] = v;
    }

    int nl4 = tid & 31;
    int jt  = tid >> 5;  // 0..15 -> one output channel per tile

    for (int ch0 = 0; ch0 < F_INF; ch0 += 16) {
        __syncthreads();
        for (int idx = tid; idx < 4 * 16 * 25; idx += 512) {
            int g = idx / (16 * 25); int r2 = idx - g * 16 * 25;
            int cl = r2 / 25; int k4 = r2 - cl * 25;
            wih4[(g * 16 + cl) * 25 + k4] =
                ((const float4*)Wih)[(g * F_INF + ch0 + cl) * 25 + k4];
        }
        for (int idx = tid; idx < 4 * 16 * 16; idx += 512) {
            int g = idx / (16 * 16); int r2 = idx - g * 16 * 16;
            int cl = r2 >> 4; int k4 = r2 & 15;
            whh4[(g * 16 + cl) * 16 + k4] =
                ((const float4*)Whh)[(g * F_INF + ch0 + cl) * 16 + k4];
        }
        __syncthreads();

        int ch = ch0 + jt;
        float ai[4], af[4], ag[4], ao[4];
        {
            float bi = bih[ch] + bhh[ch];
            float bf = bih[F_INF + ch] + bhh[F_INF + ch];
            float bg = bih[2 * F_INF + ch] + bhh[2 * F_INF + ch];
            float bo = bih[3 * F_INF + ch] + bhh[3 * F_INF + ch];
#pragma unroll
            for (int r = 0; r < 4; ++r) { ai[r] = bi; af[r] = bf; ag[r] = bg; ao[r] = bo; }
        }
        const float4* wi = wih4 + (0 * 16 + jt) * 25;
        const float4* wf = wih4 + (1 * 16 + jt) * 25;
        const float4* wg = wih4 + (2 * 16 + jt) * 25;
        const float4* wo = wih4 + (3 * 16 + jt) * 25;
        for (int k4 = 0; k4 < 25; ++k4) {
            float4 vi = wi[k4], vf = wf[k4], vg = wg[k4], vo = wo[k4];
#pragma unroll
            for (int r = 0; r < 4; ++r) {
                float4 a = acts4[(nl4 + 32 * r) * 41 + k4];
                ai[r] = dot4_(a, vi, ai[r]);
                af[r] = dot4_(a, vf, af[r]);
                ag[r] = dot4_(a, vg, ag[r]);
                ao[r] = dot4_(a, vo, ao[r]);
            }
        }
        const float4* ui = whh4 + (0 * 16 + jt) * 16;
        const float4* uf = whh4 + (1 * 16 + jt) * 16;
        const float4* ug = whh4 + (2 * 16 + jt) * 16;
        const float4* uo = whh4 + (3 * 16 + jt) * 16;
        for (int k4 = 0; k4 < 16; ++k4) {
            float4 vi = ui[k4], vf = uf[k4], vg = ug[k4], vo = uo[k4];
#pragma unroll
            for (int r = 0; r < 4; ++r) {
                float4 a = acts4[(nl4 + 32 * r) * 41 + 25 + k4];
                ai[r] = dot4_(a, vi, ai[r]);
                af[r] = dot4_(a, vf, af[r]);
                ag[r] = dot4_(a, vg, ag[r]);
                ao[r] = dot4_(a, vo, ao[r]);
            }
        }
#pragma unroll
        for (int r = 0; r < 4; ++r) {
            int n = n0 + nl4 + 32 * r;
            if (n >= N_NODES) continue;
            float ig = sigmoidf_(ai[r]);
            float fg = sigmoidf_(af[r]);
            float gg = tanhf_(ag[r]);
            float og = sigmoidf_(ao[r]);
            float cc = fg * c0in[(size_t)n * F_INF + ch] + ig * gg;
            float hh = og * tanhf_(cc);
            c1[(size_t)n * F_INF + ch] = cc;
            h1[(size_t)n * F_INF + ch] = hh;
        }
    }
}

// ---------------------------------------------------------------------------
// K5: out[n,t] = relu(h1[n,:]) @ lin_w[t,:] + lin_b[t]
// ---------------------------------------------------------------------------
__global__ void k_head(const float* __restrict__ h1, const float* __restrict__ lw,
                       const float* __restrict__ lb, float* __restrict__ out) {
    int i = blockIdx.x * blockDim.x + threadIdx.x;
    if (i >= N_NODES * T_OUT) return;
    int n = i >> 3;
    int t = i & 7;
    const float* hr = h1 + (size_t)n * F_INF;
    const float* wr = lw + (size_t)t * F_INF;
    float acc = lb[t];
#pragma unroll 8
    for (int k = 0; k < F_INF; ++k) acc += fmaxf(hr[k], 0.0f) * wr[k];
    out[i] = acc;
}

extern "C" void kernel_launch(void* const* d_in, const int* in_sizes, int n_in,
                              void* d_out, int out_size, void* d_ws, size_t ws_size,
                              hipStream_t stream) {
    const float* x     = (const float*)d_in[0];
    const int*   ei    = (const int*)d_in[1];
    const float* ew    = (const float*)d_in[2];
    const float* h0    = (const float*)d_in[3];
    const float* c0    = (const float*)d_in[4];
    const float* ggc   = (const float*)d_in[5];
    const float* gwih  = (const float*)d_in[6];
    const float* gwhh  = (const float*)d_in[7];
    const float* gbih  = (const float*)d_in[8];
    const float* gbhh  = (const float*)d_in[9];
    const float* lwih  = (const float*)d_in[10];
    const float* lwhh  = (const float*)d_in[11];
    const float* lbih  = (const float*)d_in[12];
    const float* lbhh  = (const float*)d_in[13];
    const float* lw    = (const float*)d_in[14];
    const float* lb    = (const float*)d_in[15];

    float* out = (float*)d_out;                  // [N, 8]
    float* h1  = out + (size_t)N_NODES * T_OUT;  // [N, 64]
    float* c1  = h1 + (size_t)N_NODES * F_INF;   // [N, 64]

    float* ws    = (float*)d_ws;
    float* m     = ws;                           // N*C
    float* summ  = m + (size_t)N_NODES * C_CH;   // N*C
    float* cnt   = summ + (size_t)N_NODES * C_CH;// N
    float* convh = cnt + N_NODES;                // N*C

    hipMemsetAsync(summ, 0, ((size_t)N_NODES * C_CH + N_NODES) * sizeof(float), stream);

    {
        int total = N_NODES * C_CH;
        int blocks = (total + 255) / 256;
        k_m<<<blocks, 256, 0, stream>>>(x, ggc, m);
    }
    {
        int blocks = (N_EDGES + 255) / 256;
        k_cnt<<<blocks, 256, 0, stream>>>(ei, cnt);
    }
    {
        long long total = (long long)N_EDGES * C_CH;  // 80M
        int blocks = (int)((total + 255) / 256);
        k_scatter<<<blocks, 256, 0, stream>>>(ei, ew, m, summ);
    }
    {
        int blocks = (N_NODES + 127) / 128;  // 391
        k_gru<<<blocks, 512, 0, stream>>>(x, summ, cnt, gwih, gwhh, gbih, gbhh, convh);
    }
    {
        int blocks = (N_NODES + 127) / 128;  // 391
        k_lstm<<<blocks, 512, 0, stream>>>(convh, h0, c0, lwih, lwhh, lbih, lbhh, h1, c1);
    }
    {
        int total = N_NODES * T_OUT;
        int blocks = (total + 255) / 256;
        k_head<<<blocks, 256, 0, stream>>>(h1, lw, lb, out);
    }
}

// Round 3
// 729.914 us; speedup vs baseline: 1.9837x; 1.2696x over previous
//
#include <hip/hip_runtime.h>

// Problem constants (match reference setup_inputs)
#define N_NODES 50000
#define N_EDGES 800000
#define F_INF   64
#define C_CH    100
#define T_OUT   8

__device__ __forceinline__ float sigmoidf_(float x) {
    return 1.0f / (1.0f + __expf(-x));
}
__device__ __forceinline__ float tanhf_(float x) {
    return 1.0f - 2.0f / (__expf(2.0f * x) + 1.0f);
}
__device__ __forceinline__ float dot4_(float4 a, float4 b, float acc) {
    acc += a.x * b.x; acc += a.y * b.y; acc += a.z * b.z; acc += a.w * b.w;
    return acc;
}

// ---------------------------------------------------------------------------
// CSR build stage 1: in-degree histogram (int atomics)
// ---------------------------------------------------------------------------
__global__ void k_hist(const int* __restrict__ ei, int* __restrict__ deg) {
    int e = blockIdx.x * blockDim.x + threadIdx.x;
    if (e >= N_EDGES) return;
    atomicAdd(&deg[ei[N_EDGES + e]], 1);
}

// ---------------------------------------------------------------------------
// CSR build stage 2: exclusive prefix sum over deg -> rowptr, cursor.
// Single block, 1024 threads, blocked distribution (49 items/thread).
// ---------------------------------------------------------------------------
#define SCAN_T 1024
#define SCAN_L 49  // ceil(50000/1024)
__global__ __launch_bounds__(SCAN_T) void k_scan(const int* __restrict__ deg,
                                                 int* __restrict__ rowptr,
                                                 int* __restrict__ cursor) {
    __shared__ int s[SCAN_T];
    int t = threadIdx.x;
    int base = t * SCAN_L;
    int local[SCAN_L];
    int tot = 0;
#pragma unroll
    for (int j = 0; j < SCAN_L; ++j) {
        int i = base + j;
        int v = (i < N_NODES) ? deg[i] : 0;
        local[j] = tot;  // exclusive prefix within thread
        tot += v;
    }
    s[t] = tot;
    __syncthreads();
    for (int off = 1; off < SCAN_T; off <<= 1) {
        int v = 0;
        if (t >= off) v = s[t - off];
        __syncthreads();
        s[t] += v;
        __syncthreads();
    }
    int excl = s[t] - tot;
#pragma unroll
    for (int j = 0; j < SCAN_L; ++j) {
        int i = base + j;
        if (i < N_NODES) {
            int r = excl + local[j];
            rowptr[i] = r;
            cursor[i] = r;
        }
    }
    if (t == SCAN_T - 1) rowptr[N_NODES] = s[t];  // == N_EDGES
}

// ---------------------------------------------------------------------------
// CSR build stage 3: reorder edges by dst
// ---------------------------------------------------------------------------
__global__ void k_reorder(const int* __restrict__ ei, const float* __restrict__ ew,
                          int* __restrict__ cursor,
                          int* __restrict__ col, float* __restrict__ wgt) {
    int e = blockIdx.x * blockDim.x + threadIdx.x;
    if (e >= N_EDGES) return;
    int s = ei[e];
    int d = ei[N_EDGES + e];
    int pos = atomicAdd(&cursor[d], 1);
    col[pos] = s;
    wgt[pos] = ew[e];
}

// ---------------------------------------------------------------------------
// Aggregate: xagg[n,:] = (sum_{e in row n} wgt[e] * x[col[e],:]) / max(deg,1)
// Thread = (node, k4) with k4 in 0..15 (64 channels as float4). No atomics.
// ---------------------------------------------------------------------------
__global__ void k_agg(const int* __restrict__ rowptr, const int* __restrict__ col,
                      const float* __restrict__ wgt, const float* __restrict__ x,
                      float4* __restrict__ xagg4) {
    int idx = blockIdx.x * blockDim.x + threadIdx.x;
    if (idx >= N_NODES * 16) return;
    int n  = idx >> 4;
    int k4 = idx & 15;
    int e0 = rowptr[n];
    int e1 = rowptr[n + 1];
    const float4* x4 = (const float4*)x;
    float4 acc = make_float4(0.f, 0.f, 0.f, 0.f);
    for (int e = e0; e < e1; ++e) {
        int s = col[e];
        float w = wgt[e];
        float4 xv = x4[s * 16 + k4];
        acc.x += xv.x * w; acc.y += xv.y * w; acc.z += xv.z * w; acc.w += xv.w * w;
    }
    float rc = 1.0f / fmaxf((float)(e1 - e0), 1.0f);
    acc.x *= rc; acc.y *= rc; acc.z *= rc; acc.w *= rc;
    xagg4[n * 16 + k4] = acc;
}

// ---------------------------------------------------------------------------
// K_mix: agg100[n,j] = sum_{k<64} xagg[n,k] * Wg[k*100+j]
// (only first 64 rows of ggc_w[0] matter since xp is zero-padded)
// ---------------------------------------------------------------------------
__global__ void k_mix(const float* __restrict__ xagg, const float* __restrict__ Wg,
                      float* __restrict__ agg100) {
    __shared__ float Ws[F_INF * C_CH];  // 25.6 KB
    for (int i = threadIdx.x; i < F_INF * C_CH; i += blockDim.x) Ws[i] = Wg[i];
    __syncthreads();
    int i = blockIdx.x * blockDim.x + threadIdx.x;
    if (i >= N_NODES * C_CH) return;
    int n = i / C_CH;
    int j = i - n * C_CH;
    const float* xr = xagg + n * F_INF;
    float acc = 0.0f;
#pragma unroll 8
    for (int k = 0; k < F_INF; ++k) acc += xr[k] * Ws[k * C_CH + j];
    agg100[i] = acc;
}

// ---------------------------------------------------------------------------
// K3: GRUCell -> conv_h.  Block = 512 threads, 128 nodes.
// act row = [agg(100) | x(64)] in LDS, stride 41 float4.
// agg is pre-divided (agg100).  Weights LDS-tiled 32 channels at a time.
// ---------------------------------------------------------------------------
__global__ __launch_bounds__(512) void k_gru(
    const float* __restrict__ x, const float* __restrict__ agg100,
    const float* __restrict__ Wih, const float* __restrict__ Whh,
    const float* __restrict__ bih, const float* __restrict__ bhh,
    float* __restrict__ convh) {
    __shared__ float4 acts4[128 * 41];     // 84 KB
    __shared__ float4 wih4[3 * 32 * 25];   // 38.4 KB
    __shared__ float4 whh4[3 * 32 * 16];   // 24.6 KB
    const float* acts = (const float*)acts4;
    int tid = threadIdx.x;
    int n0 = blockIdx.x * 128;

    for (int idx = tid; idx < 128 * 25; idx += 512) {
        int nl = idx / 25, k4 = idx - nl * 25;
        int n = n0 + nl;
        float4 v = make_float4(0.f, 0.f, 0.f, 0.f);
        if (n < N_NODES) v = ((const float4*)agg100)[n * 25 + k4];
        acts4[nl * 41 + k4] = v;
    }
    for (int idx = tid; idx < 128 * 16; idx += 512) {
        int nl = idx >> 4, k4 = idx & 15;
        int n = n0 + nl;
        float4 v = make_float4(0.f, 0.f, 0.f, 0.f);
        if (n < N_NODES) v = ((const float4*)x)[n * 16 + k4];
        acts4[nl * 41 + 25 + k4] = v;
    }

    int nl4 = tid & 31;
    int jt  = tid >> 5;  // 0..15

    for (int c0 = 0; c0 < C_CH; c0 += 32) {
        int tc = min(32, C_CH - c0);
        __syncthreads();
        for (int idx = tid; idx < 3 * tc * 25; idx += 512) {
            int g = idx / (tc * 25); int r2 = idx - g * tc * 25;
            int cl = r2 / 25; int k4 = r2 - cl * 25;
            wih4[(g * 32 + cl) * 25 + k4] =
                ((const float4*)Wih)[(g * C_CH + c0 + cl) * 25 + k4];
        }
        for (int idx = tid; idx < 3 * tc * 16; idx += 512) {
            int g = idx / (tc * 16); int r2 = idx - g * tc * 16;
            int cl = r2 >> 4; int k4 = r2 & 15;
            whh4[(g * 32 + cl) * 16 + k4] =
                ((const float4*)Whh)[(g * C_CH + c0 + cl) * 25 + k4];
        }
        __syncthreads();

        int cl0 = 2 * jt;
        if (cl0 >= tc) continue;
        int c = c0 + cl0;

        float ar0[4], az0[4], an0[4], hn0[4];
        float ar1[4], az1[4], an1[4], hn1[4];
        {
            float br0 = bih[c] + bhh[c];
            float bz0 = bih[C_CH + c] + bhh[C_CH + c];
            float bn0 = bih[2 * C_CH + c];
            float bhn0 = bhh[2 * C_CH + c];
            float br1 = bih[c + 1] + bhh[c + 1];
            float bz1 = bih[C_CH + c + 1] + bhh[C_CH + c + 1];
            float bn1 = bih[2 * C_CH + c + 1];
            float bhn1 = bhh[2 * C_CH + c + 1];
#pragma unroll
            for (int r = 0; r < 4; ++r) {
                ar0[r] = br0; az0[r] = bz0; an0[r] = bn0; hn0[r] = bhn0;
                ar1[r] = br1; az1[r] = bz1; an1[r] = bn1; hn1[r] = bhn1;
            }
        }
        const float4* wr0 = wih4 + (0 * 32 + cl0) * 25;
        const float4* wz0 = wih4 + (1 * 32 + cl0) * 25;
        const float4* wn0 = wih4 + (2 * 32 + cl0) * 25;
        for (int k4 = 0; k4 < 25; ++k4) {
            float4 wra = wr0[k4], wrb = wr0[25 + k4];
            float4 wza = wz0[k4], wzb = wz0[25 + k4];
            float4 wna = wn0[k4], wnb = wn0[25 + k4];
#pragma unroll
            for (int r = 0; r < 4; ++r) {
                float4 a = acts4[(nl4 + 32 * r) * 41 + k4];
                ar0[r] = dot4_(a, wra, ar0[r]);
                ar1[r] = dot4_(a, wrb, ar1[r]);
                az0[r] = dot4_(a, wza, az0[r]);
                az1[r] = dot4_(a, wzb, az1[r]);
                an0[r] = dot4_(a, wna, an0[r]);
                an1[r] = dot4_(a, wnb, an1[r]);
            }
        }
        const float4* ur0 = whh4 + (0 * 32 + cl0) * 16;
        const float4* uz0 = whh4 + (1 * 32 + cl0) * 16;
        const float4* un0 = whh4 + (2 * 32 + cl0) * 16;
        for (int k4 = 0; k4 < 16; ++k4) {
            float4 wra = ur0[k4], wrb = ur0[16 + k4];
            float4 wza = uz0[k4], wzb = uz0[16 + k4];
            float4 wna = un0[k4], wnb = un0[16 + k4];
#pragma unroll
            for (int r = 0; r < 4; ++r) {
                float4 a = acts4[(nl4 + 32 * r) * 41 + 25 + k4];
                ar0[r] = dot4_(a, wra, ar0[r]);
                ar1[r] = dot4_(a, wrb, ar1[r]);
                az0[r] = dot4_(a, wza, az0[r]);
                az1[r] = dot4_(a, wzb, az1[r]);
                hn0[r] = dot4_(a, wna, hn0[r]);
                hn1[r] = dot4_(a, wnb, hn1[r]);
            }
        }
#pragma unroll
        for (int r = 0; r < 4; ++r) {
            int n = n0 + nl4 + 32 * r;
            if (n >= N_NODES) continue;
            float rr = sigmoidf_(ar0[r]);
            float zz = sigmoidf_(az0[r]);
            float nn = tanhf_(an0[r] + rr * hn0[r]);
            float xpc = (c < F_INF) ? acts[(nl4 + 32 * r) * 164 + 100 + c] : 0.0f;
            convh[(size_t)n * C_CH + c] = (1.0f - zz) * nn + zz * xpc;
            rr = sigmoidf_(ar1[r]);
            zz = sigmoidf_(az1[r]);
            nn = tanhf_(an1[r] + rr * hn1[r]);
            xpc = (c + 1 < F_INF) ? acts[(nl4 + 32 * r) * 164 + 100 + c + 1] : 0.0f;
            convh[(size_t)n * C_CH + c + 1] = (1.0f - zz) * nn + zz * xpc;
        }
    }
}

// ---------------------------------------------------------------------------
// K4: LSTM single step -> h1, c1.  Block = 512 threads, 128 nodes.
// ---------------------------------------------------------------------------
__global__ __launch_bounds__(512) void k_lstm(
    const float* __restrict__ convh, const float* __restrict__ h0,
    const float* __restrict__ c0in,
    const float* __restrict__ Wih, const float* __restrict__ Whh,
    const float* __restrict__ bih, const float* __restrict__ bhh,
    float* __restrict__ h1, float* __restrict__ c1) {
    __shared__ float4 acts4[128 * 41];     // 84 KB
    __shared__ float4 wih4[4 * 16 * 25];   // 25.6 KB
    __shared__ float4 whh4[4 * 16 * 16];   // 16.4 KB
    int tid = threadIdx.x;
    int n0 = blockIdx.x * 128;

    for (int idx = tid; idx < 128 * 25; idx += 512) {
        int nl = idx / 25, k4 = idx - nl * 25;
        int n = n0 + nl;
        float4 v = make_float4(0.f, 0.f, 0.f, 0.f);
        if (n < N_NODES) v = ((const float4*)convh)[n * 25 + k4];
        acts4[nl * 41 + k4] = v;
    }
    for (int idx = tid; idx < 128 * 16; idx += 512) {
        int nl = idx >> 4, k4 = idx & 15;
        int n = n0 + nl;
        float4 v = make_float4(0.f, 0.f, 0.f, 0.f);
        if (n < N_NODES) v = ((const float4*)h0)[n * 16 + k4];
        acts4[nl * 41 + 25 + k4] = v;
    }

    int nl4 = tid & 31;
    int jt  = tid >> 5;  // 0..15 -> one output channel per tile

    for (int ch0 = 0; ch0 < F_INF; ch0 += 16) {
        __syncthreads();
        for (int idx = tid; idx < 4 * 16 * 25; idx += 512) {
            int g = idx / (16 * 25); int r2 = idx - g * 16 * 25;
            int cl = r2 / 25; int k4 = r2 - cl * 25;
            wih4[(g * 16 + cl) * 25 + k4] =
                ((const float4*)Wih)[(g * F_INF + ch0 + cl) * 25 + k4];
        }
        for (int idx = tid; idx < 4 * 16 * 16; idx += 512) {
            int g = idx / (16 * 16); int r2 = idx - g * 16 * 16;
            int cl = r2 >> 4; int k4 = r2 & 15;
            whh4[(g * 16 + cl) * 16 + k4] =
                ((const float4*)Whh)[(g * F_INF + ch0 + cl) * 16 + k4];
        }
        __syncthreads();

        int ch = ch0 + jt;
        float ai[4], af[4], ag[4], ao[4];
        {
            float bi = bih[ch] + bhh[ch];
            float bf = bih[F_INF + ch] + bhh[F_INF + ch];
            float bg = bih[2 * F_INF + ch] + bhh[2 * F_INF + ch];
            float bo = bih[3 * F_INF + ch] + bhh[3 * F_INF + ch];
#pragma unroll
            for (int r = 0; r < 4; ++r) { ai[r] = bi; af[r] = bf; ag[r] = bg; ao[r] = bo; }
        }
        const float4* wi = wih4 + (0 * 16 + jt) * 25;
        const float4* wf = wih4 + (1 * 16 + jt) * 25;
        const float4* wg = wih4 + (2 * 16 + jt) * 25;
        const float4* wo = wih4 + (3 * 16 + jt) * 25;
        for (int k4 = 0; k4 < 25; ++k4) {
            float4 vi = wi[k4], vf = wf[k4], vg = wg[k4], vo = wo[k4];
#pragma unroll
            for (int r = 0; r < 4; ++r) {
                float4 a = acts4[(nl4 + 32 * r) * 41 + k4];
                ai[r] = dot4_(a, vi, ai[r]);
                af[r] = dot4_(a, vf, af[r]);
                ag[r] = dot4_(a, vg, ag[r]);
                ao[r] = dot4_(a, vo, ao[r]);
            }
        }
        const float4* ui = whh4 + (0 * 16 + jt) * 16;
        const float4* uf = whh4 + (1 * 16 + jt) * 16;
        const float4* ug = whh4 + (2 * 16 + jt) * 16;
        const float4* uo = whh4 + (3 * 16 + jt) * 16;
        for (int k4 = 0; k4 < 16; ++k4) {
            float4 vi = ui[k4], vf = uf[k4], vg = ug[k4], vo = uo[k4];
#pragma unroll
            for (int r = 0; r < 4; ++r) {
                float4 a = acts4[(nl4 + 32 * r) * 41 + 25 + k4];
                ai[r] = dot4_(a, vi, ai[r]);
                af[r] = dot4_(a, vf, af[r]);
                ag[r] = dot4_(a, vg, ag[r]);
                ao[r] = dot4_(a, vo, ao[r]);
            }
        }
#pragma unroll
        for (int r = 0; r < 4; ++r) {
            int n = n0 + nl4 + 32 * r;
            if (n >= N_NODES) continue;
            float ig = sigmoidf_(ai[r]);
            float fg = sigmoidf_(af[r]);
            float gg = tanhf_(ag[r]);
            float og = sigmoidf_(ao[r]);
            float cc = fg * c0in[(size_t)n * F_INF + ch] + ig * gg;
            float hh = og * tanhf_(cc);
            c1[(size_t)n * F_INF + ch] = cc;
            h1[(size_t)n * F_INF + ch] = hh;
        }
    }
}

// ---------------------------------------------------------------------------
// K5: out[n,t] = relu(h1[n,:]) @ lin_w[t,:] + lin_b[t]
// ---------------------------------------------------------------------------
__global__ void k_head(const float* __restrict__ h1, const float* __restrict__ lw,
                       const float* __restrict__ lb, float* __restrict__ out) {
    int i = blockIdx.x * blockDim.x + threadIdx.x;
    if (i >= N_NODES * T_OUT) return;
    int n = i >> 3;
    int t = i & 7;
    const float* hr = h1 + (size_t)n * F_INF;
    const float* wr = lw + (size_t)t * F_INF;
    float acc = lb[t];
#pragma unroll 8
    for (int k = 0; k < F_INF; ++k) acc += fmaxf(hr[k], 0.0f) * wr[k];
    out[i] = acc;
}

extern "C" void kernel_launch(void* const* d_in, const int* in_sizes, int n_in,
                              void* d_out, int out_size, void* d_ws, size_t ws_size,
                              hipStream_t stream) {
    const float* x     = (const float*)d_in[0];
    const int*   ei    = (const int*)d_in[1];
    const float* ew    = (const float*)d_in[2];
    const float* h0    = (const float*)d_in[3];
    const float* c0    = (const float*)d_in[4];
    const float* ggc   = (const float*)d_in[5];
    const float* gwih  = (const float*)d_in[6];
    const float* gwhh  = (const float*)d_in[7];
    const float* gbih  = (const float*)d_in[8];
    const float* gbhh  = (const float*)d_in[9];
    const float* lwih  = (const float*)d_in[10];
    const float* lwhh  = (const float*)d_in[11];
    const float* lbih  = (const float*)d_in[12];
    const float* lbhh  = (const float*)d_in[13];
    const float* lw    = (const float*)d_in[14];
    const float* lb    = (const float*)d_in[15];

    float* out = (float*)d_out;                  // [N, 8]
    float* h1  = out + (size_t)N_NODES * T_OUT;  // [N, 64]
    float* c1  = h1 + (size_t)N_NODES * F_INF;   // [N, 64]

    // workspace layout (float4-aligned arrays first)
    float* ws     = (float*)d_ws;
    float* summ   = ws;                               // N*100 (agg100)
    float* convh  = summ + (size_t)N_NODES * C_CH;    // N*100
    float* xagg   = convh + (size_t)N_NODES * C_CH;   // N*64
    float* wgt    = xagg + (size_t)N_NODES * F_INF;   // E
    int*   col    = (int*)(wgt + N_EDGES);            // E
    int*   deg    = col + N_EDGES;                    // N
    int*   rowptr = deg + N_NODES;                    // N+1
    int*   cursor = rowptr + N_NODES + 1;             // N

    // zero deg only
    hipMemsetAsync(deg, 0, N_NODES * sizeof(int), stream);

    {
        int blocks = (N_EDGES + 255) / 256;
        k_hist<<<blocks, 256, 0, stream>>>(ei, deg);
    }
    k_scan<<<1, SCAN_T, 0, stream>>>(deg, rowptr, cursor);
    {
        int blocks = (N_EDGES + 255) / 256;
        k_reorder<<<blocks, 256, 0, stream>>>(ei, ew, cursor, col, wgt);
    }
    {
        int total = N_NODES * 16;
        int blocks = (total + 255) / 256;
        k_agg<<<blocks, 256, 0, stream>>>(rowptr, col, wgt, x, (float4*)xagg);
    }
    {
        int total = N_NODES * C_CH;
        int blocks = (total + 255) / 256;
        k_mix<<<blocks, 256, 0, stream>>>(xagg, ggc, summ);
    }
    {
        int blocks = (N_NODES + 127) / 128;  // 391
        k_gru<<<blocks, 512, 0, stream>>>(x, summ, gwih, gwhh, gbih, gbhh, convh);
    }
    {
        int blocks = (N_NODES + 127) / 128;  // 391
        k_lstm<<<blocks, 512, 0, stream>>>(convh, h0, c0, lwih, lwhh, lbih, lbhh, h1, c1);
    }
    {
        int total = N_NODES * T_OUT;
        int blocks = (total + 255) / 256;
        k_head<<<blocks, 256, 0, stream>>>(h1, lw, lb, out);
    }
}

// Round 4
// 457.535 us; speedup vs baseline: 3.1646x; 1.5953x over previous
//
#include <hip/hip_runtime.h>

// Problem constants (match reference setup_inputs)
#define N_NODES 50000
#define N_EDGES 800000
#define F_INF   64
#define C_CH    100
#define T_OUT   8

typedef unsigned short u16;
typedef unsigned int   u32;
typedef __attribute__((ext_vector_type(8))) short bf16x8;
typedef __attribute__((ext_vector_type(4))) float f32x4;

__device__ __forceinline__ float sigmoidf_(float x) {
    return 1.0f / (1.0f + __expf(-x));
}
__device__ __forceinline__ float tanhf_(float x) {
    return 1.0f - 2.0f / (__expf(2.0f * x) + 1.0f);
}
__device__ __forceinline__ u16 f2bf(float f) {
    union { float f; u32 u; } v; v.f = f;
    u32 u = v.u;
    u += 0x7FFF + ((u >> 16) & 1);   // RNE
    return (u16)(u >> 16);
}
__device__ __forceinline__ float bf2f(u16 h) {
    union { u32 u; float f; } v; v.u = ((u32)h) << 16;
    return v.f;
}

// ---------------------------------------------------------------------------
// CSR build stage 1: in-degree histogram (int atomics)
// ---------------------------------------------------------------------------
__global__ void k_hist(const int* __restrict__ ei, int* __restrict__ deg) {
    int e = blockIdx.x * blockDim.x + threadIdx.x;
    if (e >= N_EDGES) return;
    atomicAdd(&deg[ei[N_EDGES + e]], 1);
}

// ---------------------------------------------------------------------------
// CSR build stage 2: exclusive prefix sum over deg -> rowptr, cursor.
// ---------------------------------------------------------------------------
#define SCAN_T 1024
#define SCAN_L 49  // ceil(50000/1024)
__global__ __launch_bounds__(SCAN_T) void k_scan(const int* __restrict__ deg,
                                                 int* __restrict__ rowptr,
                                                 int* __restrict__ cursor) {
    __shared__ int s[SCAN_T];
    int t = threadIdx.x;
    int base = t * SCAN_L;
    int local[SCAN_L];
    int tot = 0;
#pragma unroll
    for (int j = 0; j < SCAN_L; ++j) {
        int i = base + j;
        int v = (i < N_NODES) ? deg[i] : 0;
        local[j] = tot;
        tot += v;
    }
    s[t] = tot;
    __syncthreads();
    for (int off = 1; off < SCAN_T; off <<= 1) {
        int v = 0;
        if (t >= off) v = s[t - off];
        __syncthreads();
        s[t] += v;
        __syncthreads();
    }
    int excl = s[t] - tot;
#pragma unroll
    for (int j = 0; j < SCAN_L; ++j) {
        int i = base + j;
        if (i < N_NODES) {
            int r = excl + local[j];
            rowptr[i] = r;
            cursor[i] = r;
        }
    }
    if (t == SCAN_T - 1) rowptr[N_NODES] = s[t];
}

// ---------------------------------------------------------------------------
// CSR build stage 3: reorder edges by dst
// ---------------------------------------------------------------------------
__global__ void k_reorder(const int* __restrict__ ei, const float* __restrict__ ew,
                          int* __restrict__ cursor,
                          int* __restrict__ col, float* __restrict__ wgt) {
    int e = blockIdx.x * blockDim.x + threadIdx.x;
    if (e >= N_EDGES) return;
    int s = ei[e];
    int d = ei[N_EDGES + e];
    int pos = atomicAdd(&cursor[d], 1);
    col[pos] = s;
    wgt[pos] = ew[e];
}

// ---------------------------------------------------------------------------
// Aggregate: xagg[n,:] = (sum_e wgt*x[col,:]) / max(deg,1), output bf16
// ---------------------------------------------------------------------------
__global__ void k_agg(const int* __restrict__ rowptr, const int* __restrict__ col,
                      const float* __restrict__ wgt, const float* __restrict__ x,
                      u16* __restrict__ xaggbf) {
    int idx = blockIdx.x * blockDim.x + threadIdx.x;
    if (idx >= N_NODES * 16) return;
    int n  = idx >> 4;
    int k4 = idx & 15;
    int e0 = rowptr[n];
    int e1 = rowptr[n + 1];
    const float4* x4 = (const float4*)x;
    float4 acc = make_float4(0.f, 0.f, 0.f, 0.f);
    for (int e = e0; e < e1; ++e) {
        int s = col[e];
        float w = wgt[e];
        float4 xv = x4[s * 16 + k4];
        acc.x += xv.x * w; acc.y += xv.y * w; acc.z += xv.z * w; acc.w += xv.w * w;
    }
    float rc = 1.0f / fmaxf((float)(e1 - e0), 1.0f);
    acc.x *= rc; acc.y *= rc; acc.z *= rc; acc.w *= rc;
    uint2 p;
    p.x = (u32)f2bf(acc.x) | ((u32)f2bf(acc.y) << 16);
    p.y = (u32)f2bf(acc.z) | ((u32)f2bf(acc.w) << 16);
    ((uint2*)xaggbf)[n * 16 + k4] = p;
}

// ---------------------------------------------------------------------------
// x -> bf16 (8 elements per thread)
// ---------------------------------------------------------------------------
__global__ void k_xbf(const float* __restrict__ x, u16* __restrict__ xbf) {
    int idx = blockIdx.x * blockDim.x + threadIdx.x;
    if (idx >= N_NODES * F_INF / 8) return;
    float4 a = ((const float4*)x)[idx * 2];
    float4 b = ((const float4*)x)[idx * 2 + 1];
    uint4 p;
    p.x = (u32)f2bf(a.x) | ((u32)f2bf(a.y) << 16);
    p.y = (u32)f2bf(a.z) | ((u32)f2bf(a.w) << 16);
    p.z = (u32)f2bf(b.x) | ((u32)f2bf(b.y) << 16);
    p.w = (u32)f2bf(b.z) | ((u32)f2bf(b.w) << 16);
    ((uint4*)xbf)[idx] = p;
}

// ---------------------------------------------------------------------------
// Build GRU weight buffer Wgru[4][112][128] bf16.
//  gate g in {0:r, 1:z, 2:i_n, 3:h_n}; rows c (0..111, pad>=100); k 0..127.
//  k<64  : W_comb[c,k] = sum_j gwih[(g*100+c),j] * ggc[k,j]   (g<3)
//  k>=64 : gwhh[(g*100+c), k-64]  (g in {0,1}), g==3: gwhh[(200+c), k-64]
// ---------------------------------------------------------------------------
__global__ void k_wgru(const float* __restrict__ ggc, const float* __restrict__ gwih,
                       const float* __restrict__ gwhh, u16* __restrict__ Wgru) {
    int idx = blockIdx.x * blockDim.x + threadIdx.x;
    if (idx >= 4 * 112 * 128) return;
    int g = idx / 14336;
    int r = idx - g * 14336;
    int c = r >> 7;
    int k = r & 127;
    float val = 0.0f;
    if (c < 100) {
        if (g < 3) {
            if (k < 64) {
                const float* wr = gwih + (g * 100 + c) * 100;
                const float* gr = ggc + k * 100;
                float s = 0.0f;
#pragma unroll 4
                for (int j = 0; j < 100; ++j) s += wr[j] * gr[j];
                val = s;
            } else if (g < 2) {
                val = gwhh[(g * 100 + c) * 100 + (k - 64)];
            }
        } else {
            if (k >= 64) val = gwhh[(200 + c) * 100 + (k - 64)];
        }
    }
    Wgru[idx] = f2bf(val);
}

// ---------------------------------------------------------------------------
// Build LSTM weight buffer Wl[4][64][192] bf16.
//  k<100: lwih[(g*64+c),k]; 100..127: 0; 128..191: lwhh[(g*64+c),k-128]
// ---------------------------------------------------------------------------
__global__ void k_wlstm(const float* __restrict__ lwih, const float* __restrict__ lwhh,
                        u16* __restrict__ Wl) {
    int idx = blockIdx.x * blockDim.x + threadIdx.x;
    if (idx >= 4 * 64 * 192) return;
    int g = idx / 12288;
    int r = idx - g * 12288;
    int c = r / 192;
    int k = r - c * 192;
    int row = g * 64 + c;
    float val = 0.0f;
    if (k < 100) val = lwih[row * 100 + k];
    else if (k >= 128) val = lwhh[row * 64 + (k - 128)];
    Wl[idx] = f2bf(val);
}

// ---------------------------------------------------------------------------
// Fused GRU + LSTM via MFMA bf16. Block = 256 thr (4 waves), 64 nodes.
// GRU:  A1 = [xagg(64) | x(64)] K=128; 4 gate-GEMMs (r,z,i_n,h_n), 7 c-tiles.
// LSTM: A2 = [convh(100)|0(28)|h0(64)] K=192; 4 gate-GEMMs, 4 c-tiles.
// Per-ct in-lane epilogues (all 4 gates share (lane,reg) coords).
// ---------------------------------------------------------------------------
#define A1_OFF   0          // u16[64][144] = 18432 B
#define A2_OFF   18432      // u16[64][208] = 26624 B
#define BIAS_OFF 45056      // float[600]   = 2400 B
#define BL_OFF   47456      // float[256]   = 1024 B
#define SMEM_SZ  48480
// scratch (phase 2e, overlays A1/A2): h1s float[64][68] @0, c1s @17408

__global__ __launch_bounds__(256) void k_fused(
    const u16* __restrict__ xaggbf, const u16* __restrict__ xbf,
    const float* __restrict__ h0, const float* __restrict__ c0,
    const u16* __restrict__ Wgru, const u16* __restrict__ Wl,
    const float* __restrict__ gbih, const float* __restrict__ gbhh,
    const float* __restrict__ lbih, const float* __restrict__ lbhh,
    float* __restrict__ h1, float* __restrict__ c1) {
    __shared__ char smem[SMEM_SZ];
    u16* A1 = (u16*)(smem + A1_OFF);
    u16* A2 = (u16*)(smem + A2_OFF);
    float* bias = (float*)(smem + BIAS_OFF);
    float* bl   = (float*)(smem + BL_OFF);
    int tid = threadIdx.x;
    int n0 = blockIdx.x * 64;

    // ---- stage A1: rows 64, [xaggbf | xbf], 16B chunks, stride 288 B ----
    for (int idx = tid; idx < 64 * 16; idx += 256) {
        int row = idx >> 4, ch = idx & 15;
        int n = n0 + row;
        uint4 v = make_uint4(0, 0, 0, 0);
        if (n < N_NODES)
            v = (ch < 8) ? ((const uint4*)xaggbf)[n * 8 + ch]
                         : ((const uint4*)xbf)[n * 8 + (ch - 8)];
        *(uint4*)((char*)A1 + row * 288 + ch * 16) = v;
    }
    // ---- stage A2 h0 part (cols 128..191) ----
    for (int idx = tid; idx < 64 * 16; idx += 256) {
        int row = idx >> 4, c4 = idx & 15;
        int n = n0 + row;
        float4 v = make_float4(0.f, 0.f, 0.f, 0.f);
        if (n < N_NODES) v = ((const float4*)h0)[n * 16 + c4];
        uint2 p;
        p.x = (u32)f2bf(v.x) | ((u32)f2bf(v.y) << 16);
        p.y = (u32)f2bf(v.z) | ((u32)f2bf(v.w) << 16);
        *(uint2*)((char*)A2 + row * 416 + 256 + c4 * 8) = p;
    }
    // ---- zero A2 cols 100..127 (56 B per row) ----
    for (int idx = tid; idx < 64 * 14; idx += 256) {
        int row = idx / 14, j = idx - row * 14;
        *(u32*)((char*)A2 + row * 416 + 200 + j * 4) = 0;
    }
    // ---- biases ----
    for (int idx = tid; idx < 600; idx += 256)
        bias[idx] = (idx < 300) ? gbih[idx] : gbhh[idx - 300];
    if (tid < 256) bl[tid] = lbih[tid] + lbhh[tid];
    __syncthreads();

    int w = tid >> 6, lane = tid & 63, quad = lane >> 4, ln = lane & 15;

    // ---- GEMM1 + per-ct GRU epilogue ----
    bf16x8 a1[4];
#pragma unroll
    for (int kt = 0; kt < 4; ++kt)
        a1[kt] = *(const bf16x8*)(A1 + (w * 16 + ln) * 144 + kt * 32 + quad * 8);

    for (int ct = 0; ct < 7; ++ct) {
        f32x4 ar = {0.f, 0.f, 0.f, 0.f}, az = ar, an = ar, ah = ar;
        int rb = (ct * 16 + ln) * 128 + quad * 8;
#pragma unroll
        for (int kt = 0; kt < 4; ++kt) {
            bf16x8 b0 = *(const bf16x8*)(Wgru + rb + kt * 32);
            bf16x8 b1 = *(const bf16x8*)(Wgru + 14336 + rb + kt * 32);
            bf16x8 b2 = *(const bf16x8*)(Wgru + 2 * 14336 + rb + kt * 32);
            bf16x8 b3 = *(const bf16x8*)(Wgru + 3 * 14336 + rb + kt * 32);
            ar = __builtin_amdgcn_mfma_f32_16x16x32_bf16(a1[kt], b0, ar, 0, 0, 0);
            az = __builtin_amdgcn_mfma_f32_16x16x32_bf16(a1[kt], b1, az, 0, 0, 0);
            an = __builtin_amdgcn_mfma_f32_16x16x32_bf16(a1[kt], b2, an, 0, 0, 0);
            ah = __builtin_amdgcn_mfma_f32_16x16x32_bf16(a1[kt], b3, ah, 0, 0, 0);
        }
        int c = ct * 16 + ln;
        if (c < 100) {
            float br = bias[c] + bias[300 + c];
            float bz = bias[100 + c] + bias[400 + c];
            float bn = bias[200 + c];
            float bh = bias[500 + c];
#pragma unroll
            for (int reg = 0; reg < 4; ++reg) {
                int m = w * 16 + quad * 4 + reg;
                float rv = sigmoidf_(ar[reg] + br);
                float zv = sigmoidf_(az[reg] + bz);
                float nv = tanhf_(an[reg] + bn + rv * (ah[reg] + bh));
                float xp = (c < F_INF) ? bf2f(A1[m * 144 + 64 + c]) : 0.0f;
                A2[m * 208 + c] = f2bf((1.0f - zv) * nv + zv * xp);
            }
        }
    }
    __syncthreads();

    // ---- GEMM2 + per-ct LSTM epilogue ----
    bf16x8 a2[6];
#pragma unroll
    for (int kt = 0; kt < 6; ++kt)
        a2[kt] = *(const bf16x8*)(A2 + (w * 16 + ln) * 208 + kt * 32 + quad * 8);

    float h1v[4][4], c1v[4][4];
    for (int ct = 0; ct < 4; ++ct) {
        f32x4 ai = {0.f, 0.f, 0.f, 0.f}, af = ai, ag = ai, ao = ai;
        int rb = (ct * 16 + ln) * 192 + quad * 8;
#pragma unroll
        for (int kt = 0; kt < 6; ++kt) {
            bf16x8 b0 = *(const bf16x8*)(Wl + rb + kt * 32);
            bf16x8 b1 = *(const bf16x8*)(Wl + 12288 + rb + kt * 32);
            bf16x8 b2 = *(const bf16x8*)(Wl + 2 * 12288 + rb + kt * 32);
            bf16x8 b3 = *(const bf16x8*)(Wl + 3 * 12288 + rb + kt * 32);
            ai = __builtin_amdgcn_mfma_f32_16x16x32_bf16(a2[kt], b0, ai, 0, 0, 0);
            af = __builtin_amdgcn_mfma_f32_16x16x32_bf16(a2[kt], b1, af, 0, 0, 0);
            ag = __builtin_amdgcn_mfma_f32_16x16x32_bf16(a2[kt], b2, ag, 0, 0, 0);
            ao = __builtin_amdgcn_mfma_f32_16x16x32_bf16(a2[kt], b3, ao, 0, 0, 0);
        }
        int c = ct * 16 + ln;
        float bi = bl[c], bff = bl[64 + c], bg = bl[128 + c], bo = bl[192 + c];
#pragma unroll
        for (int reg = 0; reg < 4; ++reg) {
            int m = w * 16 + quad * 4 + reg;
            int n = n0 + m;
            float iv = sigmoidf_(ai[reg] + bi);
            float fv = sigmoidf_(af[reg] + bff);
            float gv = tanhf_(ag[reg] + bg);
            float ov = sigmoidf_(ao[reg] + bo);
            float c0v = (n < N_NODES) ? c0[n * F_INF + c] : 0.0f;
            float cc = fv * c0v + iv * gv;
            c1v[ct][reg] = cc;
            h1v[ct][reg] = ov * tanhf_(cc);
        }
    }
    __syncthreads();   // A1/A2 dead; scratch overlay begins

    float* h1s = (float*)smem;             // [64][68]
    float* c1s = (float*)(smem + 17408);   // [64][68]
#pragma unroll
    for (int ct = 0; ct < 4; ++ct) {
        int c = ct * 16 + ln;
#pragma unroll
        for (int reg = 0; reg < 4; ++reg) {
            int m = w * 16 + quad * 4 + reg;
            h1s[m * 68 + c] = h1v[ct][reg];
            c1s[m * 68 + c] = c1v[ct][reg];
        }
    }
    __syncthreads();

    // ---- coalesced copy out ----
    for (int idx = tid; idx < 64 * 16; idx += 256) {
        int row = idx >> 4, c4 = idx & 15;
        int n = n0 + row;
        if (n < N_NODES) {
            ((float4*)h1)[n * 16 + c4] = *(float4*)(h1s + row * 68 + c4 * 4);
            ((float4*)c1)[n * 16 + c4] = *(float4*)(c1s + row * 68 + c4 * 4);
        }
    }
}

// ---------------------------------------------------------------------------
// K5: out[n,t] = relu(h1[n,:]) @ lin_w[t,:] + lin_b[t]
// ---------------------------------------------------------------------------
__global__ void k_head(const float* __restrict__ h1, const float* __restrict__ lw,
                       const float* __restrict__ lb, float* __restrict__ out) {
    int i = blockIdx.x * blockDim.x + threadIdx.x;
    if (i >= N_NODES * T_OUT) return;
    int n = i >> 3;
    int t = i & 7;
    const float* hr = h1 + (size_t)n * F_INF;
    const float* wr = lw + (size_t)t * F_INF;
    float acc = lb[t];
#pragma unroll 8
    for (int k = 0; k < F_INF; ++k) acc += fmaxf(hr[k], 0.0f) * wr[k];
    out[i] = acc;
}

extern "C" void kernel_launch(void* const* d_in, const int* in_sizes, int n_in,
                              void* d_out, int out_size, void* d_ws, size_t ws_size,
                              hipStream_t stream) {
    const float* x     = (const float*)d_in[0];
    const int*   ei    = (const int*)d_in[1];
    const float* ew    = (const float*)d_in[2];
    const float* h0    = (const float*)d_in[3];
    const float* c0    = (const float*)d_in[4];
    const float* ggc   = (const float*)d_in[5];
    const float* gwih  = (const float*)d_in[6];
    const float* gwhh  = (const float*)d_in[7];
    const float* gbih  = (const float*)d_in[8];
    const float* gbhh  = (const float*)d_in[9];
    const float* lwih  = (const float*)d_in[10];
    const float* lwhh  = (const float*)d_in[11];
    const float* lbih  = (const float*)d_in[12];
    const float* lbhh  = (const float*)d_in[13];
    const float* lw    = (const float*)d_in[14];
    const float* lb    = (const float*)d_in[15];

    float* out = (float*)d_out;                  // [N, 8]
    float* h1  = out + (size_t)N_NODES * T_OUT;  // [N, 64]
    float* c1  = h1 + (size_t)N_NODES * F_INF;   // [N, 64]

    // workspace layout (bytes; all 16B aligned)
    char* ws = (char*)d_ws;
    u16*   xaggbf = (u16*)ws;                                  // N*64 u16 = 6.4MB
    u16*   xbf    = (u16*)(ws + 6400000);                      // N*64 u16
    u16*   Wgru   = (u16*)(ws + 12800000);                     // 4*112*128 = 114688 B
    u16*   Wl     = (u16*)(ws + 12914688);                     // 4*64*192  = 98304 B
    float* wgt    = (float*)(ws + 13012992);                   // E
    int*   col    = (int*)(ws + 13012992 + 3200000);           // E
    int*   deg    = (int*)(ws + 13012992 + 6400000);           // N
    int*   rowptr = deg + N_NODES;                             // N+1
    int*   cursor = rowptr + N_NODES + 1;                      // N

    hipMemsetAsync(deg, 0, N_NODES * sizeof(int), stream);

    { int b = (N_EDGES + 255) / 256;
      k_hist<<<b, 256, 0, stream>>>(ei, deg); }
    k_scan<<<1, SCAN_T, 0, stream>>>(deg, rowptr, cursor);
    { int b = (N_EDGES + 255) / 256;
      k_reorder<<<b, 256, 0, stream>>>(ei, ew, cursor, col, wgt); }
    { int b = (N_NODES * 16 + 255) / 256;
      k_agg<<<b, 256, 0, stream>>>(rowptr, col, wgt, x, xaggbf); }
    { int b = (N_NODES * F_INF / 8 + 255) / 256;
      k_xbf<<<b, 256, 0, stream>>>(x, xbf); }
    { int b = (4 * 112 * 128 + 255) / 256;
      k_wgru<<<b, 256, 0, stream>>>(ggc, gwih, gwhh, Wgru); }
    { int b = (4 * 64 * 192 + 255) / 256;
      k_wlstm<<<b, 256, 0, stream>>>(lwih, lwhh, Wl); }
    { int b = (N_NODES + 63) / 64;  // 782
      k_fused<<<b, 256, 0, stream>>>(xaggbf, xbf, h0, c0, Wgru, Wl,
                                     gbih, gbhh, lbih, lbhh, h1, c1); }
    { int b = (N_NODES * T_OUT + 255) / 256;
      k_head<<<b, 256, 0, stream>>>(h1, lw, lb, out); }
}

// Round 5
// 392.793 us; speedup vs baseline: 3.6862x; 1.1648x over previous
//
#include <hip/hip_runtime.h>

// Problem constants (match reference setup_inputs)
#define N_NODES 50000
#define N_EDGES 800000
#define F_INF   64
#define C_CH    100
#define T_OUT   8

typedef unsigned short u16;
typedef unsigned int   u32;
typedef __attribute__((ext_vector_type(8))) short bf16x8;
typedef __attribute__((ext_vector_type(4))) float f32x4;

__device__ __forceinline__ float sigmoidf_(float x) {
    return 1.0f / (1.0f + __expf(-x));
}
__device__ __forceinline__ float tanhf_(float x) {
    return 1.0f - 2.0f / (__expf(2.0f * x) + 1.0f);
}
__device__ __forceinline__ u16 f2bf(float f) {
    union { float f; u32 u; } v; v.f = f;
    u32 u = v.u;
    u += 0x7FFF + ((u >> 16) & 1);   // RNE
    return (u16)(u >> 16);
}
__device__ __forceinline__ float bf2f(u16 h) {
    union { u32 u; float f; } v; v.u = ((u32)h) << 16;
    return v.f;
}

// ---------------------------------------------------------------------------
// CSR build stage 1: in-degree histogram (int atomics)
// ---------------------------------------------------------------------------
__global__ void k_hist(const int* __restrict__ ei, int* __restrict__ deg) {
    int e = blockIdx.x * blockDim.x + threadIdx.x;
    if (e >= N_EDGES) return;
    atomicAdd(&deg[ei[N_EDGES + e]], 1);
}

// ---------------------------------------------------------------------------
// CSR build stage 2: exclusive prefix sum over deg -> rowptr, cursor.
// ---------------------------------------------------------------------------
#define SCAN_T 1024
#define SCAN_L 49  // ceil(50000/1024)
__global__ __launch_bounds__(SCAN_T) void k_scan(const int* __restrict__ deg,
                                                 int* __restrict__ rowptr,
                                                 int* __restrict__ cursor) {
    __shared__ int s[SCAN_T];
    int t = threadIdx.x;
    int base = t * SCAN_L;
    int local[SCAN_L];
    int tot = 0;
#pragma unroll
    for (int j = 0; j < SCAN_L; ++j) {
        int i = base + j;
        int v = (i < N_NODES) ? deg[i] : 0;
        local[j] = tot;
        tot += v;
    }
    s[t] = tot;
    __syncthreads();
    for (int off = 1; off < SCAN_T; off <<= 1) {
        int v = 0;
        if (t >= off) v = s[t - off];
        __syncthreads();
        s[t] += v;
        __syncthreads();
    }
    int excl = s[t] - tot;
#pragma unroll
    for (int j = 0; j < SCAN_L; ++j) {
        int i = base + j;
        if (i < N_NODES) {
            int r = excl + local[j];
            rowptr[i] = r;
            cursor[i] = r;
        }
    }
    if (t == SCAN_T - 1) rowptr[N_NODES] = s[t];
}

// ---------------------------------------------------------------------------
// CSR build stage 3: reorder edges by dst
// ---------------------------------------------------------------------------
__global__ void k_reorder(const int* __restrict__ ei, const float* __restrict__ ew,
                          int* __restrict__ cursor,
                          int* __restrict__ col, float* __restrict__ wgt) {
    int e = blockIdx.x * blockDim.x + threadIdx.x;
    if (e >= N_EDGES) return;
    int s = ei[e];
    int d = ei[N_EDGES + e];
    int pos = atomicAdd(&cursor[d], 1);
    col[pos] = s;
    wgt[pos] = ew[e];
}

// ---------------------------------------------------------------------------
// Aggregate: wave per node, lane = channel.  Coalesced 256B x-row loads,
// edge metadata broadcast (same-address load across lanes). 2x unroll.
// ---------------------------------------------------------------------------
__global__ __launch_bounds__(256) void k_agg(
    const int* __restrict__ rowptr, const int* __restrict__ col,
    const float* __restrict__ wgt, const float* __restrict__ x,
    u16* __restrict__ xaggbf) {
    int node = blockIdx.x * 4 + (threadIdx.x >> 6);
    int lane = threadIdx.x & 63;
    if (node >= N_NODES) return;
    int e0 = rowptr[node];
    int e1 = rowptr[node + 1];
    float acc = 0.0f;
    int e = e0;
    for (; e + 1 < e1; e += 2) {
        int s0 = col[e], s1 = col[e + 1];
        float w0 = wgt[e], w1 = wgt[e + 1];
        acc += x[(size_t)s0 * F_INF + lane] * w0;
        acc += x[(size_t)s1 * F_INF + lane] * w1;
    }
    if (e < e1) acc += x[(size_t)col[e] * F_INF + lane] * wgt[e];
    acc /= fmaxf((float)(e1 - e0), 1.0f);
    xaggbf[(size_t)node * F_INF + lane] = f2bf(acc);
}

// ---------------------------------------------------------------------------
// Weight prep (GRU + LSTM in one launch).
// Wgru[4][112][128]: g in {r,z,i_n,h_n}; k<64: (gwih@ggc^T) (g<3); k>=64: gwhh.
// Wl[4][64][192]: k<100 lwih; 100..127 zero; 128..191 lwhh.
// ---------------------------------------------------------------------------
#define WGRU_ELEMS (4 * 112 * 128)
#define WL_ELEMS   (4 * 64 * 192)
__global__ void k_wprep(const float* __restrict__ ggc, const float* __restrict__ gwih,
                        const float* __restrict__ gwhh,
                        const float* __restrict__ lwih, const float* __restrict__ lwhh,
                        u16* __restrict__ Wgru, u16* __restrict__ Wl) {
    int idx = blockIdx.x * blockDim.x + threadIdx.x;
    if (idx < WGRU_ELEMS) {
        int g = idx / 14336;
        int r = idx - g * 14336;
        int c = r >> 7;
        int k = r & 127;
        float val = 0.0f;
        if (c < 100) {
            if (g < 3) {
                if (k < 64) {
                    const float* wr = gwih + (g * 100 + c) * 100;
                    const float* gr = ggc + k * 100;
                    float s = 0.0f;
#pragma unroll 4
                    for (int j = 0; j < 100; ++j) s += wr[j] * gr[j];
                    val = s;
                } else if (g < 2) {
                    val = gwhh[(g * 100 + c) * 100 + (k - 64)];
                }
            } else {
                if (k >= 64) val = gwhh[(200 + c) * 100 + (k - 64)];
            }
        }
        Wgru[idx] = f2bf(val);
    } else if (idx < WGRU_ELEMS + WL_ELEMS) {
        int i2 = idx - WGRU_ELEMS;
        int g = i2 / 12288;
        int r = i2 - g * 12288;
        int c = r / 192;
        int k = r - c * 192;
        int row = g * 64 + c;
        float val = 0.0f;
        if (k < 100) val = lwih[row * 100 + k];
        else if (k >= 128) val = lwhh[row * 64 + (k - 128)];
        Wl[i2] = f2bf(val);
    }
}

// ---------------------------------------------------------------------------
// Fused GRU + LSTM + head via MFMA bf16.  Block = 256 thr (4 waves), 64 nodes.
// Wave-ct specialization: wave w owns column tiles ct=w,(w+4); iterates all 4
// node subtiles (mt).  Each weight byte loaded once per block.
// A1 stride 152 u16 (19 x 16B chunks, 3 mod 8 -> conflict-free b128).
// A2 stride 216 u16 (27 chunks, 3 mod 8).
// LDS map (bytes): A1 @0 (19456) | A2 @19456 (27648) | bias @47104 (2400)
//                  bl @49504 (1024) | lwf @50528 (2048) | lbs @52576 (32)
// scratch overlay after GEMM2: h1s float[64][68] @0, c1s @17408.
// ---------------------------------------------------------------------------
#define A1S 152
#define A2S 216
__global__ __launch_bounds__(256, 3) void k_fused(
    const u16* __restrict__ xaggbf, const float* __restrict__ x,
    const float* __restrict__ h0, const float* __restrict__ c0,
    const u16* __restrict__ Wgru, const u16* __restrict__ Wl,
    const float* __restrict__ gbih, const float* __restrict__ gbhh,
    const float* __restrict__ lbih, const float* __restrict__ lbhh,
    const float* __restrict__ lw, const float* __restrict__ lb,
    float* __restrict__ out, float* __restrict__ h1, float* __restrict__ c1) {
    __shared__ char smem[52608];
    u16*   A1   = (u16*)(smem);
    u16*   A2   = (u16*)(smem + 19456);
    float* bias = (float*)(smem + 47104);
    float* bl   = (float*)(smem + 49504);
    float* lwf  = (float*)(smem + 50528);   // [k*8+t]
    float* lbs  = (float*)(smem + 52576);
    int tid = threadIdx.x;
    int n0 = blockIdx.x * 64;

    // ---- stage A1 cols 0..63: xagg bf16 ----
    for (int idx = tid; idx < 512; idx += 256) {
        int row = idx >> 3, ch = idx & 7;
        int n = n0 + row;
        uint4 v = make_uint4(0, 0, 0, 0);
        if (n < N_NODES) v = ((const uint4*)xaggbf)[n * 8 + ch];
        *(uint4*)(A1 + row * A1S + ch * 8) = v;
    }
    // ---- stage A1 cols 64..127: x fp32 -> bf16 ----
    for (int idx = tid; idx < 512; idx += 256) {
        int row = idx >> 3, ch = idx & 7;
        int n = n0 + row;
        uint4 p = make_uint4(0, 0, 0, 0);
        if (n < N_NODES) {
            float4 f0 = ((const float4*)x)[n * 16 + ch * 2];
            float4 f1 = ((const float4*)x)[n * 16 + ch * 2 + 1];
            p.x = (u32)f2bf(f0.x) | ((u32)f2bf(f0.y) << 16);
            p.y = (u32)f2bf(f0.z) | ((u32)f2bf(f0.w) << 16);
            p.z = (u32)f2bf(f1.x) | ((u32)f2bf(f1.y) << 16);
            p.w = (u32)f2bf(f1.z) | ((u32)f2bf(f1.w) << 16);
        }
        *(uint4*)(A1 + row * A1S + 64 + ch * 8) = p;
    }
    // ---- stage A2 cols 128..191: h0 fp32 -> bf16 ----
    for (int idx = tid; idx < 512; idx += 256) {
        int row = idx >> 3, ch = idx & 7;
        int n = n0 + row;
        uint4 p = make_uint4(0, 0, 0, 0);
        if (n < N_NODES) {
            float4 f0 = ((const float4*)h0)[n * 16 + ch * 2];
            float4 f1 = ((const float4*)h0)[n * 16 + ch * 2 + 1];
            p.x = (u32)f2bf(f0.x) | ((u32)f2bf(f0.y) << 16);
            p.y = (u32)f2bf(f0.z) | ((u32)f2bf(f0.w) << 16);
            p.z = (u32)f2bf(f1.x) | ((u32)f2bf(f1.y) << 16);
            p.w = (u32)f2bf(f1.z) | ((u32)f2bf(f1.w) << 16);
        }
        *(uint4*)(A2 + row * A2S + 128 + ch * 8) = p;
    }
    // ---- zero A2 cols 100..127 ----
    for (int idx = tid; idx < 64 * 14; idx += 256) {
        int row = idx / 14, j = idx - row * 14;
        *(u32*)((char*)A2 + row * (A2S * 2) + 200 + j * 4) = 0;
    }
    // ---- biases + head weights ----
    for (int idx = tid; idx < 600; idx += 256)
        bias[idx] = (idx < 300) ? gbih[idx] : gbhh[idx - 300];
    if (tid < 256) bl[tid] = lbih[tid] + lbhh[tid];
    for (int idx = tid; idx < 512; idx += 256) {
        int k = idx >> 3, t = idx & 7;
        lwf[idx] = lw[t * F_INF + k];
    }
    if (tid < 8) lbs[tid] = lb[tid];
    __syncthreads();

    int w = tid >> 6, lane = tid & 63, quad = lane >> 4, ln = lane & 15;

    // ================= GEMM1: GRU gates, wave handles ct = w, w+4 =========
    for (int ct = w; ct < 7; ct += 4) {
        f32x4 ar[4], az[4], an[4], ah[4];
#pragma unroll
        for (int mt = 0; mt < 4; ++mt) {
            ar[mt] = (f32x4){0.f, 0.f, 0.f, 0.f};
            az[mt] = ar[mt]; an[mt] = ar[mt]; ah[mt] = ar[mt];
        }
        int rb = (ct * 16 + ln) * 128 + quad * 8;
#pragma unroll
        for (int kt = 0; kt < 4; ++kt) {
            bf16x8 b0 = *(const bf16x8*)(Wgru + rb + kt * 32);
            bf16x8 b1 = *(const bf16x8*)(Wgru + 14336 + rb + kt * 32);
            bf16x8 b2 = *(const bf16x8*)(Wgru + 2 * 14336 + rb + kt * 32);
            bf16x8 b3 = *(const bf16x8*)(Wgru + 3 * 14336 + rb + kt * 32);
#pragma unroll
            for (int mt = 0; mt < 4; ++mt) {
                bf16x8 a = *(const bf16x8*)(A1 + (mt * 16 + ln) * A1S + kt * 32 + quad * 8);
                ar[mt] = __builtin_amdgcn_mfma_f32_16x16x32_bf16(a, b0, ar[mt], 0, 0, 0);
                az[mt] = __builtin_amdgcn_mfma_f32_16x16x32_bf16(a, b1, az[mt], 0, 0, 0);
                an[mt] = __builtin_amdgcn_mfma_f32_16x16x32_bf16(a, b2, an[mt], 0, 0, 0);
                ah[mt] = __builtin_amdgcn_mfma_f32_16x16x32_bf16(a, b3, ah[mt], 0, 0, 0);
            }
        }
        int c = ct * 16 + ln;
        if (c < 100) {
            float br = bias[c] + bias[300 + c];
            float bz = bias[100 + c] + bias[400 + c];
            float bn = bias[200 + c];
            float bh = bias[500 + c];
#pragma unroll
            for (int mt = 0; mt < 4; ++mt) {
#pragma unroll
                for (int reg = 0; reg < 4; ++reg) {
                    int m = mt * 16 + quad * 4 + reg;
                    float rv = sigmoidf_(ar[mt][reg] + br);
                    float zv = sigmoidf_(az[mt][reg] + bz);
                    float nv = tanhf_(an[mt][reg] + bn + rv * (ah[mt][reg] + bh));
                    float xp = (c < F_INF) ? bf2f(A1[m * A1S + 64 + c]) : 0.0f;
                    A2[m * A2S + c] = f2bf((1.0f - zv) * nv + zv * xp);
                }
            }
        }
    }
    __syncthreads();

    // ================= GEMM2: LSTM gates, wave handles ct = w =============
    float h1v[4][4], c1v[4][4];
    {
        int ct = w;  // 0..3
        f32x4 ai[4], af[4], ag[4], ao[4];
#pragma unroll
        for (int mt = 0; mt < 4; ++mt) {
            ai[mt] = (f32x4){0.f, 0.f, 0.f, 0.f};
            af[mt] = ai[mt]; ag[mt] = ai[mt]; ao[mt] = ai[mt];
        }
        int rb = (ct * 16 + ln) * 192 + quad * 8;
#pragma unroll
        for (int kt = 0; kt < 6; ++kt) {
            bf16x8 b0 = *(const bf16x8*)(Wl + rb + kt * 32);
            bf16x8 b1 = *(const bf16x8*)(Wl + 12288 + rb + kt * 32);
            bf16x8 b2 = *(const bf16x8*)(Wl + 2 * 12288 + rb + kt * 32);
            bf16x8 b3 = *(const bf16x8*)(Wl + 3 * 12288 + rb + kt * 32);
#pragma unroll
            for (int mt = 0; mt < 4; ++mt) {
                bf16x8 a = *(const bf16x8*)(A2 + (mt * 16 + ln) * A2S + kt * 32 + quad * 8);
                ai[mt] = __builtin_amdgcn_mfma_f32_16x16x32_bf16(a, b0, ai[mt], 0, 0, 0);
                af[mt] = __builtin_amdgcn_mfma_f32_16x16x32_bf16(a, b1, af[mt], 0, 0, 0);
                ag[mt] = __builtin_amdgcn_mfma_f32_16x16x32_bf16(a, b2, ag[mt], 0, 0, 0);
                ao[mt] = __builtin_amdgcn_mfma_f32_16x16x32_bf16(a, b3, ao[mt], 0, 0, 0);
            }
        }
        int c = ct * 16 + ln;  // < 64
        float bi = bl[c], bff = bl[64 + c], bg = bl[128 + c], bo = bl[192 + c];
#pragma unroll
        for (int mt = 0; mt < 4; ++mt) {
#pragma unroll
            for (int reg = 0; reg < 4; ++reg) {
                int m = mt * 16 + quad * 4 + reg;
                int n = n0 + m;
                float iv = sigmoidf_(ai[mt][reg] + bi);
                float fv = sigmoidf_(af[mt][reg] + bff);
                float gv = tanhf_(ag[mt][reg] + bg);
                float ov = sigmoidf_(ao[mt][reg] + bo);
                float c0v = (n < N_NODES) ? c0[(size_t)n * F_INF + c] : 0.0f;
                float cc = fv * c0v + iv * gv;
                c1v[mt][reg] = cc;
                h1v[mt][reg] = ov * tanhf_(cc);
            }
        }
    }
    __syncthreads();   // A1/A2 dead; scratch overlay begins

    float* h1s = (float*)smem;             // [64][68]
    float* c1s = (float*)(smem + 17408);   // [64][68]
    {
        int c = w * 16 + ln;
#pragma unroll
        for (int mt = 0; mt < 4; ++mt) {
#pragma unroll
            for (int reg = 0; reg < 4; ++reg) {
                int m = mt * 16 + quad * 4 + reg;
                h1s[m * 68 + c] = h1v[mt][reg];
                c1s[m * 68 + c] = c1v[mt][reg];
            }
        }
    }
    __syncthreads();

    // ---- fused head: out[n,t] = relu(h1[n,:]) @ lw^T + lb ----
    for (int o = tid; o < 512; o += 256) {
        int nl = o >> 3, t = o & 7;
        float acc = lbs[t];
        const float* hr = h1s + nl * 68;
#pragma unroll 8
        for (int k = 0; k < F_INF; ++k)
            acc += fmaxf(hr[k], 0.0f) * lwf[k * 8 + t];
        int n = n0 + nl;
        if (n < N_NODES) out[(size_t)n * T_OUT + t] = acc;
    }
    // ---- coalesced h1/c1 stores ----
    for (int idx = tid; idx < 64 * 16; idx += 256) {
        int row = idx >> 4, c4 = idx & 15;
        int n = n0 + row;
        if (n < N_NODES) {
            ((float4*)h1)[n * 16 + c4] = *(float4*)(h1s + row * 68 + c4 * 4);
            ((float4*)c1)[n * 16 + c4] = *(float4*)(c1s + row * 68 + c4 * 4);
        }
    }
}

extern "C" void kernel_launch(void* const* d_in, const int* in_sizes, int n_in,
                              void* d_out, int out_size, void* d_ws, size_t ws_size,
                              hipStream_t stream) {
    const float* x     = (const float*)d_in[0];
    const int*   ei    = (const int*)d_in[1];
    const float* ew    = (const float*)d_in[2];
    const float* h0    = (const float*)d_in[3];
    const float* c0    = (const float*)d_in[4];
    const float* ggc   = (const float*)d_in[5];
    const float* gwih  = (const float*)d_in[6];
    const float* gwhh  = (const float*)d_in[7];
    const float* gbih  = (const float*)d_in[8];
    const float* gbhh  = (const float*)d_in[9];
    const float* lwih  = (const float*)d_in[10];
    const float* lwhh  = (const float*)d_in[11];
    const float* lbih  = (const float*)d_in[12];
    const float* lbhh  = (const float*)d_in[13];
    const float* lw    = (const float*)d_in[14];
    const float* lb    = (const float*)d_in[15];

    float* out = (float*)d_out;                  // [N, 8]
    float* h1  = out + (size_t)N_NODES * T_OUT;  // [N, 64]
    float* c1  = h1 + (size_t)N_NODES * F_INF;   // [N, 64]

    // workspace layout (bytes; all 16B aligned)
    char* ws = (char*)d_ws;
    u16*   xaggbf = (u16*)ws;                                  // N*64 u16 = 6.4MB
    u16*   Wgru   = (u16*)(ws + 6400000);                      // 114688 B
    u16*   Wl     = (u16*)(ws + 6514688);                      // 98304 B
    float* wgt    = (float*)(ws + 6612992);                    // E
    int*   col    = (int*)(ws + 6612992 + 3200000);            // E
    int*   deg    = (int*)(ws + 6612992 + 6400000);            // N
    int*   rowptr = deg + N_NODES;                             // N+1
    int*   cursor = rowptr + N_NODES + 1;                      // N

    hipMemsetAsync(deg, 0, N_NODES * sizeof(int), stream);

    { int b = (N_EDGES + 255) / 256;
      k_hist<<<b, 256, 0, stream>>>(ei, deg); }
    k_scan<<<1, SCAN_T, 0, stream>>>(deg, rowptr, cursor);
    { int b = (N_EDGES + 255) / 256;
      k_reorder<<<b, 256, 0, stream>>>(ei, ew, cursor, col, wgt); }
    { int b = (N_NODES + 3) / 4;  // wave per node
      k_agg<<<b, 256, 0, stream>>>(rowptr, col, wgt, x, xaggbf); }
    { int b = (WGRU_ELEMS + WL_ELEMS + 255) / 256;
      k_wprep<<<b, 256, 0, stream>>>(ggc, gwih, gwhh, lwih, lwhh, Wgru, Wl); }
    { int b = (N_NODES + 63) / 64;  // 782
      k_fused<<<b, 256, 0, stream>>>(xaggbf, x, h0, c0, Wgru, Wl,
                                     gbih, gbhh, lbih, lbhh, lw, lb,
                                     out, h1, c1); }
}